// Round 7
// baseline (62.161 us; speedup 1.0000x reference)
//
#include <hip/hip_runtime.h>
#include <math.h>

// ThermostatNN: B independent 40-step rollouts of a 2->64->1 MLP plant +
// hysteresis thermostat. One thread per batch element.
//
// R7 change vs R6 (theory: allocator spills pinned/uniform values to AGPRs
// and LICM keeps re-hoisting C-level LDS loads; every scheme measured
// ~440-484 VALU insts/step vs ~227 in source, the delta being
// v_accvgpr_read copies):
//  - Weight reads are now inline-asm ds_read_b128: asm volatile can NEVER
//    be hoisted out of the loop, so weights are re-read from LDS each step
//    and never become register-resident (=> nothing to park in AGPRs).
//  - The s_waitcnt lgkmcnt(0) is inside the same asm block that defines the
//    outputs, so all consumers are data-dependent on it (no rule-18 hazard).
//  - 4 chunks/step x 8 broadcast ds_read_b128 (all lanes same address:
//    conflict-free, ~1-2 clk each on the LDS pipe, hidden under VALU).
//  - Only c[64] (per-thread) stays register-pinned; transient pressure is
//    8 quads = 32 VGPRs per chunk -> total ~121 VGPRs, comfortably inside
//    the __launch_bounds__(256,3) budget of 168 -> no eviction pressure.
//
// NUMERICS (do not touch): serial single-accumulator dot in ascending-j
// order, expf-based stable sigmoid, explicitly rounded updates. absmax ==
// 0.0 vs reference in R1-R6; op order and rounding must stay bit-identical.

#define LHID 64
#define NSTEPS 40

typedef __attribute__((ext_vector_type(4))) float f32x4;

__global__ __launch_bounds__(256, 3) void thermostat_kernel(
    const float* __restrict__ x_init,  // (B,4): step, isOn, temp, aux
    const float* __restrict__ W1,      // (2,64) row-major
    const float* __restrict__ b1,      // (64)
    const float* __restrict__ W2,      // (64,1)
    const float* __restrict__ b2,      // (1)
    float* __restrict__ out,           // (40,B)
    int B)
{
    // LDS layout: bytes [0,256) = W1 row 0 (a), bytes [256,512) = W2.
    __shared__ __align__(16) float lds_w[2 * LHID];

    int tid = threadIdx.x;
    if (tid < 2 * LHID) {
        lds_w[tid] = (tid < LHID) ? W1[tid] : W2[tid - LHID];
    }
    __syncthreads();

    int b = blockIdx.x * blockDim.x + tid;
    if (b >= B) return;

    float4 st = reinterpret_cast<const float4*>(x_init)[b];
    float step0 = st.x;
    float isOn  = st.y;
    float temp  = st.z;
    float aux   = st.w;
    float bias2 = b2[0];

    int n_active = (int)fminf(fmaxf((float)NSTEPS - step0, 0.0f), (float)NSTEPS);

    // Per-thread invariant part of layer 1: c[j] = aux*W1[1][j] + b1[j].
    float c[LHID];
#pragma unroll
    for (int j = 0; j < LHID; j += 4) {
        float4 vr1 = *reinterpret_cast<const float4*>(&W1[LHID + j]);
        float4 vb  = *reinterpret_cast<const float4*>(&b1[j]);
        c[j+0] = fmaf(aux, vr1.x, vb.x);
        c[j+1] = fmaf(aux, vr1.y, vb.y);
        c[j+2] = fmaf(aux, vr1.z, vb.z);
        c[j+3] = fmaf(aux, vr1.w, vb.w);
    }
#pragma unroll
    for (int j = 0; j < LHID; ++j) {
        asm volatile("" : "+v"(c[j]));
    }

    // 32-bit LDS byte address (shared aperture is 4 GiB aligned, so the low
    // 32 bits of the generic pointer are the LDS offset).
    unsigned lbase = (unsigned)(uintptr_t)(void*)lds_w;

    float* po = out + b;

    // One chunk: 4 a-quads + 4 w2-quads loaded by asm (never hoistable),
    // then 16 hidden units in exact serial order.
#define LOAD_CHUNK(A0,A1,A2,A3,AW0,AW1,AW2,AW3)                                \
    asm volatile("ds_read_b128 %0, %8 offset:" #A0 "\n\t"                      \
                 "ds_read_b128 %1, %8 offset:" #A1 "\n\t"                      \
                 "ds_read_b128 %2, %8 offset:" #A2 "\n\t"                      \
                 "ds_read_b128 %3, %8 offset:" #A3 "\n\t"                      \
                 "ds_read_b128 %4, %8 offset:" #AW0 "\n\t"                     \
                 "ds_read_b128 %5, %8 offset:" #AW1 "\n\t"                     \
                 "ds_read_b128 %6, %8 offset:" #AW2 "\n\t"                     \
                 "ds_read_b128 %7, %8 offset:" #AW3 "\n\t"                     \
                 "s_waitcnt lgkmcnt(0)"                                        \
                 : "=&v"(qa0), "=&v"(qa1), "=&v"(qa2), "=&v"(qa3),             \
                   "=&v"(qw0), "=&v"(qw1), "=&v"(qw2), "=&v"(qw3)              \
                 : "v"(lbase))

#define UNIT(AV, WV, CJ)                                                       \
    acc = fmaf(fmaxf(fmaf(temp, (AV), (CJ)), 0.0f), (WV), acc)

#define CHUNK_MATH(J0)                                                         \
    UNIT(qa0[0], qw0[0], c[(J0)+0]);  UNIT(qa0[1], qw0[1], c[(J0)+1]);         \
    UNIT(qa0[2], qw0[2], c[(J0)+2]);  UNIT(qa0[3], qw0[3], c[(J0)+3]);         \
    UNIT(qa1[0], qw1[0], c[(J0)+4]);  UNIT(qa1[1], qw1[1], c[(J0)+5]);         \
    UNIT(qa1[2], qw1[2], c[(J0)+6]);  UNIT(qa1[3], qw1[3], c[(J0)+7]);         \
    UNIT(qa2[0], qw2[0], c[(J0)+8]);  UNIT(qa2[1], qw2[1], c[(J0)+9]);         \
    UNIT(qa2[2], qw2[2], c[(J0)+10]); UNIT(qa2[3], qw2[3], c[(J0)+11]);        \
    UNIT(qa3[0], qw3[0], c[(J0)+12]); UNIT(qa3[1], qw3[1], c[(J0)+13]);        \
    UNIT(qa3[2], qw3[2], c[(J0)+14]); UNIT(qa3[3], qw3[3], c[(J0)+15])

#pragma unroll 1
    for (int t = 0; t < NSTEPS; ++t) {
        float acc = 0.0f;
        {
            f32x4 qa0, qa1, qa2, qa3, qw0, qw1, qw2, qw3;
            LOAD_CHUNK(0, 16, 32, 48, 256, 272, 288, 304);
            CHUNK_MATH(0);
        }
        {
            f32x4 qa0, qa1, qa2, qa3, qw0, qw1, qw2, qw3;
            LOAD_CHUNK(64, 80, 96, 112, 320, 336, 352, 368);
            CHUNK_MATH(16);
        }
        {
            f32x4 qa0, qa1, qa2, qa3, qw0, qw1, qw2, qw3;
            LOAD_CHUNK(128, 144, 160, 176, 384, 400, 416, 432);
            CHUNK_MATH(32);
        }
        {
            f32x4 qa0, qa1, qa2, qa3, qw0, qw1, qw2, qw3;
            LOAD_CHUNK(192, 208, 224, 240, 448, 464, 480, 496);
            CHUNK_MATH(48);
        }

        float x = __fadd_rn(acc, bias2);

        // stable sigmoid, single exact division (bitwise == two-branch form)
        float e = expf(-fabsf(x));
        float num = (x >= 0.0f) ? 1.0f : e;
        float s = num / (1.0f + e);

        // plant = s*10 - 5 ; dtemp = plant*10
        float plant = __fsub_rn(__fmul_rn(s, 10.0f), 5.0f);
        float dtemp = __fmul_rn(plant, 10.0f);

        float tn_off = __fadd_rn(temp, dtemp);
        float tn_on  = __fadd_rn(tn_off, 5.0f);

        bool off = (isOn <= 0.5f);
        float temp_new = off ? tn_off : tn_on;
        float isOn_new;
        if (off) isOn_new = (temp_new <= 66.0f) ? 1.0f : isOn;
        else     isOn_new = (temp_new <= 78.0f) ? isOn : 0.0f;

        if (t < n_active) {
            temp = temp_new;
            isOn = isOn_new;
        }

        *po = temp;
        po += B;
    }
#undef LOAD_CHUNK
#undef UNIT
#undef CHUNK_MATH
}

extern "C" void kernel_launch(void* const* d_in, const int* in_sizes, int n_in,
                              void* d_out, int out_size, void* d_ws, size_t ws_size,
                              hipStream_t stream) {
    const float* x_init = (const float*)d_in[0];
    const float* W1     = (const float*)d_in[1];
    const float* b1     = (const float*)d_in[2];
    const float* W2     = (const float*)d_in[3];
    const float* b2     = (const float*)d_in[4];
    float* out = (float*)d_out;

    int B = in_sizes[0] / 4;
    int threads = 256;
    int blocks = (B + threads - 1) / threads;
    thermostat_kernel<<<blocks, threads, 0, stream>>>(x_init, W1, b1, W2, b2, out, B);
}